// Round 8
// baseline (14404.979 us; speedup 1.0000x reference)
//
#include <hip/hip_runtime.h>

// R8: intra-CU wave-specialized 2-layer LSTM. 16 blocks x 512 threads.
//  - Waves 0-3 ("L0 crew"): layer-0 recurrence, 8 gate-tiles each
//    (tiles v,v+4,...,v+28 -> all 4 gates of col-blocks v and v+4).
//    Weights Whh0 + x/bias kfrag in regs (40 frags = 160 VGPR).
//  - Waves 4-7 ("L1 crew"): layer-1 recurrence LAGGED 1 step: iter k computes
//    h1(k-1) from {h1(k-2), h0(k-1)} - both pre-barrier -> ONE barrier/step.
//    Whh1 in regs (32 frags = 128 VGPR); Wih1 A-frags read per step from a
//    pre-scaled frag-linear image in d_ws (L2-resident, coalesced dwordx4),
//    staged once by lstm_stageA (stream-ordered, graph-safe).
//  - Each SIMD hosts 1 L0 + 1 L1 wave -> independent chains interleave (ILP).
//  - No cross-CU sync. LDS 22KB. Fallback: proven R2 kernel if ws too small.

typedef short bf16x8 __attribute__((ext_vector_type(8)));
typedef float f32x4 __attribute__((ext_vector_type(4)));
typedef unsigned long long ull;

static constexpr int CIN = 12, T = 2048, H = 128;
static constexpr int NTHR = 512;
static constexpr float L2E = 1.4426950408889634f;
static constexpr size_t WS_NEED = 131072;   // Wih1 frag image (pre-scaled bf16)

// LDS map (main kernel)
static constexpr int LH0 = 0;        // 2 x 4096  h0 dbuf (B-frag image)
static constexpr int LH1 = 8192;     // 2 x 4096  h1 dbuf
static constexpr int LX  = 16384;    // 2 x 1024  x dbuf (k=12 col = 1.0 -> L0 bias)
static constexpr int LB1 = 18432;    // 2048      L1 bias f32 (pre-scaled)
static constexpr int LRED= 20480;    // 2048      epilogue reduction
static constexpr int LDS_SZ = 22528;

#if __has_builtin(__builtin_amdgcn_exp2f)
#define EXP2(x) __builtin_amdgcn_exp2f(x)
#else
#define EXP2(x) exp2f(x)
#endif

__device__ __forceinline__ unsigned f2bf(float f) {  // f32 -> bf16 bits, RTNE
  unsigned u = __builtin_bit_cast(unsigned, f);
  return (u + 0x7FFFu + ((u >> 16) & 1u)) >> 16;
}

__device__ __forceinline__ unsigned cvtpk_bf16(float lo, float hi) {
  unsigned r;
  asm("v_cvt_pk_bf16_f32 %0, %1, %2" : "=v"(r) : "v"(lo), "v"(hi));
  return r;
}

__device__ __forceinline__ float sig_pre(float a) {  // 1/(1+2^a)
  return __builtin_amdgcn_rcpf(1.f + EXP2(a));
}

// ---- stager: pre-scaled frag-linear Wih1 image into ws ----
// chunk c -> (tau=c>>8, kf=(c>>6)&3, lane=c&63); lane holds
// W[tau*16+(lane&15)][kf*32+(lane>>4)*8 ..+8] * s(gate)
__global__ void lstm_stageA(const float* __restrict__ Wih1, char* __restrict__ ws) {
  const int c   = blockIdx.x * 512 + threadIdx.x;   // 0..8191
  const int tau = c >> 8, rem = c & 255, kf = rem >> 6, ll = rem & 63;
  const int n  = tau * 16 + (ll & 15);
  const int k0 = kf * 32 + (ll >> 4) * 8;
  const float s = ((tau >> 3) == 2) ? (2.f * L2E) : (-L2E);
  bf16x8 v;
  #pragma unroll
  for (int j = 0; j < 8; ++j) v[j] = (short)f2bf(Wih1[n * H + k0 + j] * s);
  *(bf16x8*)(ws + (size_t)c * 16) = v;
}

// ============================ main kernel ============================
__global__ __launch_bounds__(NTHR, 2) void lstm_crew(
    const float* __restrict__ xg,
    const float* __restrict__ Wih0, const float* __restrict__ Whh0,
    const float* __restrict__ bih0, const float* __restrict__ bhh0,
    const float* __restrict__ Wih1, const float* __restrict__ Whh1,
    const float* __restrict__ bih1, const float* __restrict__ bhh1,
    const float* __restrict__ Wd,   const float* __restrict__ bd,
    float* __restrict__ out, const char* __restrict__ wsA)
{
  __shared__ char lds[LDS_SZ];
  const int tid = threadIdx.x;
  const int l  = tid & 63;
  const int w  = tid >> 6;        // wave 0..7
  const int lg = l >> 4;          // lane k-group 0..3
  const int lr = l & 15;          // A-row-in-tile / batch column
  const int v  = w & 3;           // crew-local wave id
  const bool isL0 = (w < 4);
  const int b0 = blockIdx.x * 16;

  // ---- zero h/x state ----
  for (int i = tid; i < 18432 / 4; i += NTHR) ((int*)lds)[i] = 0;
  // ---- L1 bias image (pre-scaled f32) ----
  {
    const float s = ((tid >> 7) == 2) ? (2.f * L2E) : (-L2E);
    ((float*)(lds + LB1))[tid] = (bih1[tid] + bhh1[tid]) * s;
  }
  __syncthreads();
  // const-1.0 column at k==12 of both X buffers (pairs with L0 bias column)
  if (tid < 32) {
    const int buf = tid >> 4, b = tid & 15;
    *(unsigned short*)(lds + LX + buf * 1024 + 256 + b * 16 + 8) = 0x3F80;
  }

  // ---- per-crew weight registers ----
  // tiles tau = v + 4*i, i=0..7. gate = tau>>3 = i>>1; col-block = v + 4*(i&1).
  bf16x8 A0[8][5];   // L0 crew: Whh0 (kf 0..3) + x/bias kfrag (kf 4)
  bf16x8 W1r[8][4];  // L1 crew: Whh1
  if (isL0) {
    #pragma unroll
    for (int i = 0; i < 8; ++i) {
      const int tau = v + 4 * i;
      const int n = tau * 16 + lr;
      const float s = ((tau >> 3) == 2) ? (2.f * L2E) : (-L2E);
      #pragma unroll
      for (int kf = 0; kf < 4; ++kf) {
        const float* src = &Whh0[n * H + kf * 32 + lg * 8];
        #pragma unroll
        for (int j = 0; j < 8; ++j) A0[i][kf][j] = (short)f2bf(src[j] * s);
      }
      #pragma unroll
      for (int j = 0; j < 8; ++j) {
        const int k = lg * 8 + j;
        float val = 0.f;
        if (k < CIN) val = Wih0[n * CIN + k] * s;
        else if (k == CIN) val = (bih0[n] + bhh0[n]) * s;
        A0[i][4][j] = (short)f2bf(val);
      }
    }
  } else {
    #pragma unroll
    for (int i = 0; i < 8; ++i) {
      const int tau = v + 4 * i;
      const int n = tau * 16 + lr;
      const float s = ((tau >> 3) == 2) ? (2.f * L2E) : (-L2E);
      #pragma unroll
      for (int kf = 0; kf < 4; ++kf) {
        const float* src = &Whh1[n * H + kf * 32 + lg * 8];
        #pragma unroll
        for (int j = 0; j < 8; ++j) W1r[i][kf][j] = (short)f2bf(src[j] * s);
      }
    }
  }

  // per-lane geometry
  const int rdB = lg * 256 + lr * 16;   // B-frag read base
  // h-image write offsets for col-blocks v and v+4 (8B each: 4 cols, lg*4 aligned)
  int wrT[2];
  #pragma unroll
  for (int j = 0; j < 2; ++j) {
    const int colb = (v + 4 * j) * 16 + lg * 4;
    wrT[j] = (colb >> 3) * 256 + lr * 16 + (colb & 7) * 2;
  }
  // x loader role (threads 0..191, inside L0 crew)
  const int xb = tid & 15, xc = tid >> 4;
  const int wrX = (xc >> 3) * 256 + xb * 16 + (xc & 7) * 2;
  const size_t xbase = (size_t)(b0 + xb) * (CIN * T) + (size_t)xc * T;
  if (tid < 192)
    *(unsigned short*)(lds + LX + wrX) = (unsigned short)f2bf(xg[xbase]);
  __syncthreads();

  float c0v[8] = {0,0,0,0,0,0,0,0};
  float c1v[8] = {0,0,0,0,0,0,0,0};
  const f32x4 zed = {0.f, 0.f, 0.f, 0.f};

  // main loop: iter k does L0(k) and L1(k-1). read H*[rd], write H*[p].
  #pragma unroll 2
  for (int k = 0; k < T; ++k) {
    const int p = k & 1, rd = 1 - p;
    if (isL0) {
      float xnext = 0.f;
      if (tid < 192) xnext = xg[xbase + (k + 1 < T ? k + 1 : k)];
      bf16x8 bf[5];
      #pragma unroll
      for (int kf = 0; kf < 4; ++kf)
        bf[kf] = *(const bf16x8*)(lds + LH0 + rd * 4096 + kf * 1024 + rdB);
      bf[4] = *(const bf16x8*)(lds + LX + p * 1024 + rdB);
      f32x4 acc[8];
      #pragma unroll
      for (int i = 0; i < 8; ++i) acc[i] = zed;
      #pragma unroll
      for (int kf = 0; kf < 5; ++kf)
        #pragma unroll
        for (int i = 0; i < 8; ++i)
          acc[i] = __builtin_amdgcn_mfma_f32_16x16x32_bf16(A0[i][kf], bf[kf], acc[i], 0, 0, 0);
      // ew per col-block slot j: gates at acc[2g+j]
      #pragma unroll
      for (int j = 0; j < 2; ++j) {
        float hh[4];
        #pragma unroll
        for (int r = 0; r < 4; ++r) {
          const float iv = sig_pre(acc[0 + j][r]);
          const float fv = sig_pre(acc[2 + j][r]);
          const float gv = fmaf(-2.f, sig_pre(acc[4 + j][r]), 1.f);
          const float ov = sig_pre(acc[6 + j][r]);
          const float c  = fmaf(fv, c0v[j * 4 + r], iv * gv);
          c0v[j * 4 + r] = c;
          const float th = fmaf(-2.f, sig_pre(c * (2.f * L2E)), 1.f);
          hh[r] = ov * th;
        }
        const unsigned hp0 = cvtpk_bf16(hh[0], hh[1]);
        const unsigned hp1 = cvtpk_bf16(hh[2], hh[3]);
        *(ull*)(lds + LH0 + p * 4096 + wrT[j]) = ((ull)hp1 << 32) | hp0;
      }
      if (tid < 192)
        *(unsigned short*)(lds + LX + rd * 1024 + wrX) =
            (unsigned short)cvtpk_bf16(xnext, xnext);
    } else if (k > 0) {
      bf16x8 b1f[4], b0f[4];
      #pragma unroll
      for (int kf = 0; kf < 4; ++kf) {
        b1f[kf] = *(const bf16x8*)(lds + LH1 + rd * 4096 + kf * 1024 + rdB);
        b0f[kf] = *(const bf16x8*)(lds + LH0 + rd * 4096 + kf * 1024 + rdB);
      }
      f32x4 acc[8];
      #pragma unroll
      for (int i = 0; i < 8; ++i)
        acc[i] = *(const f32x4*)(lds + LB1 + (v + 4 * i) * 64 + lg * 16);
      #pragma unroll
      for (int kf = 0; kf < 4; ++kf)
        #pragma unroll
        for (int i = 0; i < 8; ++i)
          acc[i] = __builtin_amdgcn_mfma_f32_16x16x32_bf16(W1r[i][kf], b1f[kf], acc[i], 0, 0, 0);
      #pragma unroll
      for (int kf = 0; kf < 4; ++kf) {
        bf16x8 af[8];
        #pragma unroll
        for (int i = 0; i < 8; ++i)
          af[i] = *(const bf16x8*)(wsA + (((v + 4 * i) * 4 + kf) * 1024 + l * 16));
        #pragma unroll
        for (int i = 0; i < 8; ++i)
          acc[i] = __builtin_amdgcn_mfma_f32_16x16x32_bf16(af[i], b0f[kf], acc[i], 0, 0, 0);
      }
      #pragma unroll
      for (int j = 0; j < 2; ++j) {
        float hh[4];
        #pragma unroll
        for (int r = 0; r < 4; ++r) {
          const float iv = sig_pre(acc[0 + j][r]);
          const float fv = sig_pre(acc[2 + j][r]);
          const float gv = fmaf(-2.f, sig_pre(acc[4 + j][r]), 1.f);
          const float ov = sig_pre(acc[6 + j][r]);
          const float c  = fmaf(fv, c1v[j * 4 + r], iv * gv);
          c1v[j * 4 + r] = c;
          const float th = fmaf(-2.f, sig_pre(c * (2.f * L2E)), 1.f);
          hh[r] = ov * th;
        }
        const unsigned hp0 = cvtpk_bf16(hh[0], hh[1]);
        const unsigned hp1 = cvtpk_bf16(hh[2], hh[3]);
        *(ull*)(lds + LH1 + p * 4096 + wrT[j]) = ((ull)hp1 << 32) | hp0;
      }
    }
    __syncthreads();
  }

  // ---- tail: L1 step k=T -> h1(T-1) in regs (reads H1[1], H0[1]; T even) ----
  float h1f[8];
  if (!isL0) {
    bf16x8 b1f[4], b0f[4];
    #pragma unroll
    for (int kf = 0; kf < 4; ++kf) {
      b1f[kf] = *(const bf16x8*)(lds + LH1 + 4096 + kf * 1024 + rdB);
      b0f[kf] = *(const bf16x8*)(lds + LH0 + 4096 + kf * 1024 + rdB);
    }
    f32x4 acc[8];
    #pragma unroll
    for (int i = 0; i < 8; ++i)
      acc[i] = *(const f32x4*)(lds + LB1 + (v + 4 * i) * 64 + lg * 16);
    #pragma unroll
    for (int kf = 0; kf < 4; ++kf)
      #pragma unroll
      for (int i = 0; i < 8; ++i)
        acc[i] = __builtin_amdgcn_mfma_f32_16x16x32_bf16(W1r[i][kf], b1f[kf], acc[i], 0, 0, 0);
    #pragma unroll
    for (int kf = 0; kf < 4; ++kf) {
      bf16x8 af[8];
      #pragma unroll
      for (int i = 0; i < 8; ++i)
        af[i] = *(const bf16x8*)(wsA + (((v + 4 * i) * 4 + kf) * 1024 + l * 16));
      #pragma unroll
      for (int i = 0; i < 8; ++i)
        acc[i] = __builtin_amdgcn_mfma_f32_16x16x32_bf16(af[i], b0f[kf], acc[i], 0, 0, 0);
    }
    #pragma unroll
    for (int j = 0; j < 2; ++j)
      #pragma unroll
      for (int r = 0; r < 4; ++r) {
        const float iv = sig_pre(acc[0 + j][r]);
        const float fv = sig_pre(acc[2 + j][r]);
        const float gv = fmaf(-2.f, sig_pre(acc[4 + j][r]), 1.f);
        const float ov = sig_pre(acc[6 + j][r]);
        const float c  = fmaf(fv, c1v[j * 4 + r], iv * gv);
        const float th = fmaf(-2.f, sig_pre(c * (2.f * L2E)), 1.f);
        h1f[j * 4 + r] = ov * th;
      }
    // feats + dense partials
    #pragma unroll
    for (int j = 0; j < 2; ++j) {
      const int cb = v + 4 * j;
      const int colb = cb * 16 + lg * 4;
      const float4 wd4 = *(const float4*)&Wd[colb];
      const float partial = h1f[j*4+0]*wd4.x + h1f[j*4+1]*wd4.y +
                            h1f[j*4+2]*wd4.z + h1f[j*4+3]*wd4.w;
      ((float*)(lds + LRED))[lr * 32 + cb * 4 + lg] = partial;
      float4 o4;
      o4.x = h1f[j*4+0]; o4.y = h1f[j*4+1]; o4.z = h1f[j*4+2]; o4.w = h1f[j*4+3];
      *(float4*)(&out[256 + (size_t)(b0 + lr) * H + colb]) = o4;
    }
  }
  __syncthreads();
  if (tid < 16) {
    float s = 0.f;
    #pragma unroll 8
    for (int m = 0; m < 32; ++m) s += ((float*)(lds + LRED))[tid * 32 + m];
    out[b0 + tid] = __builtin_amdgcn_rcpf(1.f + EXP2(-(s + bd[0]) * L2E));
  }
}

// ============================ fallback: R2 single kernel ============================
__global__ __launch_bounds__(NTHR, 2) void lstm_single(
    const float* __restrict__ xg,
    const float* __restrict__ Wih0, const float* __restrict__ Whh0,
    const float* __restrict__ bih0, const float* __restrict__ bhh0,
    const float* __restrict__ Wih1, const float* __restrict__ Whh1,
    const float* __restrict__ bih1, const float* __restrict__ bhh1,
    const float* __restrict__ Wd,   const float* __restrict__ bd,
    float* __restrict__ out)
{
  constexpr int LDS_H0 = 0, LDS_H1 = 8192, LDS_X = 16384, LDS_RED = 18432, LDS_SZ2 = 20480;
  __shared__ char lds[LDS_SZ2];
  const int tid = threadIdx.x;
  const int l  = tid & 63;
  const int w  = tid >> 6;
  const int lg = l >> 4;
  const int lr = l & 15;
  const int b0 = blockIdx.x * 16;

  for (int i = tid; i < LDS_SZ2 / 4; i += NTHR) ((int*)lds)[i] = 0;
  __syncthreads();
  if (tid < 32) {
    const int buf = tid >> 4, b = tid & 15;
    *(unsigned short*)(lds + LDS_X + buf * 1024 + 256 + b * 16 + 8) = 0x3F80;
  }

  bf16x8 A0[4][5];
  bf16x8 A1[4][8];
  f32x4 b1r[4];
  #pragma unroll
  for (int q = 0; q < 4; ++q) {
    const int n = (q * 8 + w) * 16 + lr;
    const float s = (q == 2) ? (2.f * L2E) : (-L2E);
    #pragma unroll
    for (int kf = 0; kf < 4; ++kf) {
      const float* src = &Whh0[n * H + kf * 32 + lg * 8];
      #pragma unroll
      for (int j = 0; j < 8; ++j) A0[q][kf][j] = (short)f2bf(src[j] * s);
    }
    #pragma unroll
    for (int j = 0; j < 8; ++j) {
      const int k = lg * 8 + j;
      float val = 0.f;
      if (k < CIN) val = Wih0[n * CIN + k] * s;
      else if (k == CIN) val = (bih0[n] + bhh0[n]) * s;
      A0[q][4][j] = (short)f2bf(val);
    }
    #pragma unroll
    for (int kf = 0; kf < 4; ++kf) {
      const float* srcA = &Whh1[n * H + kf * 32 + lg * 8];
      const float* srcB = &Wih1[n * H + kf * 32 + lg * 8];
      #pragma unroll
      for (int j = 0; j < 8; ++j) {
        A1[q][kf][j]     = (short)f2bf(srcA[j] * s);
        A1[q][4 + kf][j] = (short)f2bf(srcB[j] * s);
      }
    }
    #pragma unroll
    for (int r = 0; r < 4; ++r) {
      const int nd = (q * 8 + w) * 16 + lg * 4 + r;
      b1r[q][r] = (bih1[nd] + bhh1[nd]) * s;
    }
  }
  const f32x4 zed = {0.f, 0.f, 0.f, 0.f};

  const int rdB  = lg * 256 + lr * 16;
  const int bcol = w * 16 + lg * 4;
  const int wrH  = (bcol >> 3) * 256 + lr * 16 + (bcol & 7) * 2;
  const int xb = tid & 15, xc = tid >> 4;
  const int wrX = (xc >> 3) * 256 + xb * 16 + (xc & 7) * 2;
  const size_t xbase = (size_t)(b0 + xb) * (CIN * T) + (size_t)xc * T;

  if (tid < 192)
    *(unsigned short*)(lds + LDS_X + wrX) = (unsigned short)f2bf(xg[xbase]);
  __syncthreads();

  float c0v[4] = {0.f, 0.f, 0.f, 0.f};
  float c1v[4] = {0.f, 0.f, 0.f, 0.f};
  float h1v[4] = {0.f, 0.f, 0.f, 0.f};

  #pragma unroll 2
  for (int t = 0; t < T; ++t) {
    const int p = t & 1;
    float xnext = 0.f;
    if (tid < 192) xnext = xg[xbase + (t + 1 < T ? t + 1 : t)];

    f32x4 acc[4];
    #pragma unroll
    for (int q = 0; q < 4; ++q) acc[q] = zed;
    #pragma unroll
    for (int kf = 0; kf < 5; ++kf) {
      const int src = (kf < 4) ? (LDS_H0 + p * 4096 + kf * 1024 + rdB)
                               : (LDS_X + p * 1024 + rdB);
      const bf16x8 bf = *(const bf16x8*)(lds + src);
      #pragma unroll
      for (int q = 0; q < 4; ++q)
        acc[q] = __builtin_amdgcn_mfma_f32_16x16x32_bf16(A0[q][kf], bf, acc[q], 0, 0, 0);
    }
    {
      float h0t[4];
      #pragma unroll
      for (int r = 0; r < 4; ++r) {
        const float iv = sig_pre(acc[0][r]);
        const float fv = sig_pre(acc[1][r]);
        const float gv = fmaf(-2.f, sig_pre(acc[2][r]), 1.f);
        const float ov = sig_pre(acc[3][r]);
        const float c  = fmaf(fv, c0v[r], iv * gv);
        c0v[r] = c;
        const float th = fmaf(-2.f, sig_pre(c * (2.f * L2E)), 1.f);
        h0t[r] = ov * th;
      }
      const unsigned hp0 = cvtpk_bf16(h0t[0], h0t[1]);
      const unsigned hp1 = cvtpk_bf16(h0t[2], h0t[3]);
      *(ull*)(lds + LDS_H0 + (1 - p) * 4096 + wrH) = ((ull)hp1 << 32) | hp0;
    }
    if (tid < 192) {
      *(unsigned short*)(lds + LDS_X + (1 - p) * 1024 + wrX) =
          (unsigned short)cvtpk_bf16(xnext, xnext);
    }
    __syncthreads();

    #pragma unroll
    for (int q = 0; q < 4; ++q) acc[q] = b1r[q];
    #pragma unroll
    for (int kf = 0; kf < 8; ++kf) {
      const int src = (kf < 4)
          ? (LDS_H1 + p * 4096 + kf * 1024 + rdB)
          : (LDS_H0 + (1 - p) * 4096 + (kf - 4) * 1024 + rdB);
      const bf16x8 bf = *(const bf16x8*)(lds + src);
      #pragma unroll
      for (int q = 0; q < 4; ++q)
        acc[q] = __builtin_amdgcn_mfma_f32_16x16x32_bf16(A1[q][kf], bf, acc[q], 0, 0, 0);
    }
    {
      #pragma unroll
      for (int r = 0; r < 4; ++r) {
        const float iv = sig_pre(acc[0][r]);
        const float fv = sig_pre(acc[1][r]);
        const float gv = fmaf(-2.f, sig_pre(acc[2][r]), 1.f);
        const float ov = sig_pre(acc[3][r]);
        const float c  = fmaf(fv, c1v[r], iv * gv);
        c1v[r] = c;
        const float th = fmaf(-2.f, sig_pre(c * (2.f * L2E)), 1.f);
        h1v[r] = ov * th;
      }
      const unsigned hp0 = cvtpk_bf16(h1v[0], h1v[1]);
      const unsigned hp1 = cvtpk_bf16(h1v[2], h1v[3]);
      *(ull*)(lds + LDS_H1 + (1 - p) * 4096 + wrH) = ((ull)hp1 << 32) | hp0;
    }
    __syncthreads();
  }

  const float4 wd = *(const float4*)&Wd[bcol];
  const float partial = h1v[0] * wd.x + h1v[1] * wd.y + h1v[2] * wd.z + h1v[3] * wd.w;
  #pragma unroll
  for (int r = 0; r < 4; ++r)
    out[256 + (size_t)(b0 + lr) * H + (bcol + r)] = h1v[r];
  ((float*)(lds + LDS_RED))[tid] = partial;
  __syncthreads();
  if (tid < 16) {
    float s = 0.f;
    #pragma unroll 8
    for (int k = 0; k < 32; ++k) s += ((float*)(lds + LDS_RED))[tid + 16 * k];
    out[b0 + tid] = __builtin_amdgcn_rcpf(1.f + EXP2(-(s + bd[0]) * L2E));
  }
}

extern "C" void kernel_launch(void* const* d_in, const int* in_sizes, int n_in,
                              void* d_out, int out_size, void* d_ws, size_t ws_size,
                              hipStream_t stream) {
  const float* x    = (const float*)d_in[0];
  // d_in[1] = seq_lengths : unused by the reference
  const float* Wih0 = (const float*)d_in[2];
  const float* Whh0 = (const float*)d_in[3];
  const float* bih0 = (const float*)d_in[4];
  const float* bhh0 = (const float*)d_in[5];
  const float* Wih1 = (const float*)d_in[6];
  const float* Whh1 = (const float*)d_in[7];
  const float* bih1 = (const float*)d_in[8];
  const float* bhh1 = (const float*)d_in[9];
  const float* Wd   = (const float*)d_in[10];
  const float* bd   = (const float*)d_in[11];
  (void)in_sizes; (void)n_in; (void)out_size;

  if (ws_size >= WS_NEED && d_ws != nullptr) {
    lstm_stageA<<<dim3(16), dim3(512), 0, stream>>>(Wih1, (char*)d_ws);
    lstm_crew<<<dim3(16), dim3(NTHR), 0, stream>>>(
        x, Wih0, Whh0, bih0, bhh0, Wih1, Whh1, bih1, bhh1, Wd, bd,
        (float*)d_out, (const char*)d_ws);
  } else {
    lstm_single<<<dim3(16), dim3(NTHR), 0, stream>>>(
        x, Wih0, Whh0, bih0, bhh0, Wih1, Whh1, bih1, bhh1, Wd, bd, (float*)d_out);
  }
}

// Round 9
// 10516.100 us; speedup vs baseline: 1.3698x; 1.3698x over previous
//
#include <hip/hip_runtime.h>

// R9: intra-CU wave-specialized 2-layer LSTM, Wih1 resident in LDS.
// 16 blocks x 512 threads, one block per batch group of 16.
//  - Waves 0-3 ("L0 crew"): layer-0 recurrence, 8 gate-tiles each.
//    Weights Whh0 + x/bias kfrag in regs (40 frags = 160 VGPR).
//  - Waves 4-7 ("L1 crew"): layer-1 recurrence LAGGED 1 step: iter k computes
//    h1(k-1) from {h1(k-2), h0(k-1)} -> both pre-barrier -> ONE barrier/step.
//    Whh1 in regs (32 frags); Wih1 A-frags ds_read_b128 from a pre-scaled
//    128KB LDS frag image (staged once in-kernel, coalesced).  [R8's per-step
//    GLOBAL weight reads were the 3x regression: vmcnt-gated 200-900cyc loads
//    on the critical path. ds_read is ~120cyc with batched lgkmcnt.]
//  - Each SIMD hosts 1 L0 + 1 L1 wave -> two independent chains interleave.
//  - LDS 150KB total (fits 160KB/CU; >64KB static works on gfx950).

typedef short bf16x8 __attribute__((ext_vector_type(8)));
typedef float f32x4 __attribute__((ext_vector_type(4)));
typedef unsigned long long ull;

static constexpr int CIN = 12, T = 2048, H = 128;
static constexpr int NTHR = 512;
static constexpr float L2E = 1.4426950408889634f;

// LDS map
static constexpr int LW1 = 0;         // 131072  Wih1 frag image (pre-scaled bf16)
static constexpr int LH0 = 131072;    // 2 x 4096  h0 dbuf (B-frag image)
static constexpr int LH1 = 139264;    // 2 x 4096  h1 dbuf
static constexpr int LX  = 147456;    // 2 x 1024  x dbuf (k=12 col = 1.0 -> L0 bias)
static constexpr int LB1 = 149504;    // 2048      L1 bias f32 (pre-scaled)
static constexpr int LRED= 151552;    // 2048      epilogue reduction
static constexpr int LDS_SZ = 153600; // 150 KB

#if __has_builtin(__builtin_amdgcn_exp2f)
#define EXP2(x) __builtin_amdgcn_exp2f(x)
#else
#define EXP2(x) exp2f(x)
#endif

__device__ __forceinline__ unsigned f2bf(float f) {  // f32 -> bf16 bits, RTNE
  unsigned u = __builtin_bit_cast(unsigned, f);
  return (u + 0x7FFFu + ((u >> 16) & 1u)) >> 16;
}

__device__ __forceinline__ unsigned cvtpk_bf16(float lo, float hi) {
  unsigned r;
  asm("v_cvt_pk_bf16_f32 %0, %1, %2" : "=v"(r) : "v"(lo), "v"(hi));
  return r;
}

__device__ __forceinline__ float sig_pre(float a) {  // 1/(1+2^a)
  return __builtin_amdgcn_rcpf(1.f + EXP2(a));
}

// ============================ main kernel ============================
__global__ __launch_bounds__(NTHR, 2) void lstm_crew(
    const float* __restrict__ xg,
    const float* __restrict__ Wih0, const float* __restrict__ Whh0,
    const float* __restrict__ bih0, const float* __restrict__ bhh0,
    const float* __restrict__ Wih1, const float* __restrict__ Whh1,
    const float* __restrict__ bih1, const float* __restrict__ bhh1,
    const float* __restrict__ Wd,   const float* __restrict__ bd,
    float* __restrict__ out)
{
  __shared__ char lds[LDS_SZ];
  const int tid = threadIdx.x;
  const int l  = tid & 63;
  const int w  = tid >> 6;        // wave 0..7
  const int lg = l >> 4;          // lane k-group 0..3
  const int lr = l & 15;          // A-row-in-tile / batch column
  const int v  = w & 3;           // crew-local wave id
  const bool isL0 = (w < 4);
  const int b0 = blockIdx.x * 16;

  // ---- zero h/x state region ----
  for (int i = tid; i < 18432 / 4; i += NTHR) ((int*)(lds + LH0))[i] = 0;
  // ---- stage Wih1 -> LDS frag image (pre-scaled bf16), coalesced ----
  {
    const float4* Wv = (const float4*)Wih1;   // 16384 float4s
    #pragma unroll 4
    for (int i = 0; i < 32; ++i) {
      const int idx = i * 512 + tid;          // float4 index
      const float4 f = Wv[idx];
      const int e0 = idx * 4;                 // element index
      const int n = e0 >> 7, k = e0 & 127;    // row 0..511, col 0..124 (mult of 4)
      const int tau = n >> 4;
      const float s = ((tau >> 3) == 2) ? (2.f * L2E) : (-L2E);
      const int lane = ((k >> 3) & 3) * 16 + (n & 15);
      const int byte = ((tau * 4 + (k >> 5)) * 64 + lane) * 16 + (k & 7) * 2;
      const unsigned lo = cvtpk_bf16(f.x * s, f.y * s);
      const unsigned hi = cvtpk_bf16(f.z * s, f.w * s);
      *(ull*)(lds + LW1 + byte) = ((ull)hi << 32) | lo;   // 8B, 8-aligned
    }
  }
  // ---- L1 bias image (pre-scaled f32) ----
  {
    const float s = ((tid >> 7) == 2) ? (2.f * L2E) : (-L2E);
    ((float*)(lds + LB1))[tid] = (bih1[tid] + bhh1[tid]) * s;
  }
  __syncthreads();
  // const-1.0 column at k==12 of both X buffers (pairs with L0 bias column)
  if (tid < 32) {
    const int buf = tid >> 4, b = tid & 15;
    *(unsigned short*)(lds + LX + buf * 1024 + 256 + b * 16 + 8) = 0x3F80;
  }

  // ---- per-crew weight registers ----
  // tiles tau = v + 4*i, i=0..7. gate = tau>>3 = i>>1; col-block = v + 4*(i&1).
  bf16x8 A0[8][5];   // L0 crew: Whh0 (kf 0..3) + x/bias kfrag (kf 4)
  bf16x8 W1r[8][4];  // L1 crew: Whh1
  if (isL0) {
    #pragma unroll
    for (int i = 0; i < 8; ++i) {
      const int tau = v + 4 * i;
      const int n = tau * 16 + lr;
      const float s = ((tau >> 3) == 2) ? (2.f * L2E) : (-L2E);
      #pragma unroll
      for (int kf = 0; kf < 4; ++kf) {
        const float* src = &Whh0[n * H + kf * 32 + lg * 8];
        #pragma unroll
        for (int j = 0; j < 8; ++j) A0[i][kf][j] = (short)f2bf(src[j] * s);
      }
      #pragma unroll
      for (int j = 0; j < 8; ++j) {
        const int k = lg * 8 + j;
        float val = 0.f;
        if (k < CIN) val = Wih0[n * CIN + k] * s;
        else if (k == CIN) val = (bih0[n] + bhh0[n]) * s;
        A0[i][4][j] = (short)f2bf(val);
      }
    }
  } else {
    #pragma unroll
    for (int i = 0; i < 8; ++i) {
      const int tau = v + 4 * i;
      const int n = tau * 16 + lr;
      const float s = ((tau >> 3) == 2) ? (2.f * L2E) : (-L2E);
      #pragma unroll
      for (int kf = 0; kf < 4; ++kf) {
        const float* src = &Whh1[n * H + kf * 32 + lg * 8];
        #pragma unroll
        for (int j = 0; j < 8; ++j) W1r[i][kf][j] = (short)f2bf(src[j] * s);
      }
    }
  }

  // per-lane geometry
  const int rdB = lg * 256 + lr * 16;   // B-frag read base
  int wrT[2];                           // h-image write offsets (col-blocks v, v+4)
  #pragma unroll
  for (int j = 0; j < 2; ++j) {
    const int colb = (v + 4 * j) * 16 + lg * 4;
    wrT[j] = (colb >> 3) * 256 + lr * 16 + (colb & 7) * 2;
  }
  // x loader role (threads 0..191, inside L0 crew)
  const int xb = tid & 15, xc = tid >> 4;
  const int wrX = (xc >> 3) * 256 + xb * 16 + (xc & 7) * 2;
  const size_t xbase = (size_t)(b0 + xb) * (CIN * T) + (size_t)xc * T;
  if (tid < 192)
    *(unsigned short*)(lds + LX + wrX) = (unsigned short)f2bf(xg[xbase]);
  __syncthreads();

  float c0v[8] = {0,0,0,0,0,0,0,0};
  float c1v[8] = {0,0,0,0,0,0,0,0};
  const f32x4 zed = {0.f, 0.f, 0.f, 0.f};

  // main loop: iter k does L0(k) and L1(k-1). read H*[rd], write H*[p].
  #pragma unroll 2
  for (int k = 0; k < T; ++k) {
    const int p = k & 1, rd = 1 - p;
    if (isL0) {
      float xnext = 0.f;
      if (tid < 192) xnext = xg[xbase + (k + 1 < T ? k + 1 : k)];
      bf16x8 bf[5];
      #pragma unroll
      for (int kf = 0; kf < 4; ++kf)
        bf[kf] = *(const bf16x8*)(lds + LH0 + rd * 4096 + kf * 1024 + rdB);
      bf[4] = *(const bf16x8*)(lds + LX + p * 1024 + rdB);
      f32x4 acc[8];
      #pragma unroll
      for (int i = 0; i < 8; ++i) acc[i] = zed;
      #pragma unroll
      for (int kf = 0; kf < 5; ++kf)
        #pragma unroll
        for (int i = 0; i < 8; ++i)
          acc[i] = __builtin_amdgcn_mfma_f32_16x16x32_bf16(A0[i][kf], bf[kf], acc[i], 0, 0, 0);
      // ew per col-block slot j: gates at acc[2g+j]
      #pragma unroll
      for (int j = 0; j < 2; ++j) {
        float hh[4];
        #pragma unroll
        for (int r = 0; r < 4; ++r) {
          const float iv = sig_pre(acc[0 + j][r]);
          const float fv = sig_pre(acc[2 + j][r]);
          const float gv = fmaf(-2.f, sig_pre(acc[4 + j][r]), 1.f);
          const float ov = sig_pre(acc[6 + j][r]);
          const float c  = fmaf(fv, c0v[j * 4 + r], iv * gv);
          c0v[j * 4 + r] = c;
          const float th = fmaf(-2.f, sig_pre(c * (2.f * L2E)), 1.f);
          hh[r] = ov * th;
        }
        const unsigned hp0 = cvtpk_bf16(hh[0], hh[1]);
        const unsigned hp1 = cvtpk_bf16(hh[2], hh[3]);
        *(ull*)(lds + LH0 + p * 4096 + wrT[j]) = ((ull)hp1 << 32) | hp0;
      }
      if (tid < 192)
        *(unsigned short*)(lds + LX + rd * 1024 + wrX) =
            (unsigned short)cvtpk_bf16(xnext, xnext);
    } else if (k > 0) {
      bf16x8 b1f[4], b0f[4];
      #pragma unroll
      for (int kf = 0; kf < 4; ++kf) {
        b1f[kf] = *(const bf16x8*)(lds + LH1 + rd * 4096 + kf * 1024 + rdB);
        b0f[kf] = *(const bf16x8*)(lds + LH0 + rd * 4096 + kf * 1024 + rdB);
      }
      f32x4 acc[8];
      #pragma unroll
      for (int i = 0; i < 8; ++i)
        acc[i] = *(const f32x4*)(lds + LB1 + (v + 4 * i) * 64 + lg * 16);
      #pragma unroll
      for (int kf = 0; kf < 4; ++kf)
        #pragma unroll
        for (int i = 0; i < 8; ++i)
          acc[i] = __builtin_amdgcn_mfma_f32_16x16x32_bf16(W1r[i][kf], b1f[kf], acc[i], 0, 0, 0);
      #pragma unroll
      for (int kf = 0; kf < 4; ++kf) {
        bf16x8 af[8];
        #pragma unroll
        for (int i = 0; i < 8; ++i)
          af[i] = *(const bf16x8*)(lds + LW1 + ((v + 4 * i) * 4 + kf) * 1024 + l * 16);
        #pragma unroll
        for (int i = 0; i < 8; ++i)
          acc[i] = __builtin_amdgcn_mfma_f32_16x16x32_bf16(af[i], b0f[kf], acc[i], 0, 0, 0);
      }
      #pragma unroll
      for (int j = 0; j < 2; ++j) {
        float hh[4];
        #pragma unroll
        for (int r = 0; r < 4; ++r) {
          const float iv = sig_pre(acc[0 + j][r]);
          const float fv = sig_pre(acc[2 + j][r]);
          const float gv = fmaf(-2.f, sig_pre(acc[4 + j][r]), 1.f);
          const float ov = sig_pre(acc[6 + j][r]);
          const float c  = fmaf(fv, c1v[j * 4 + r], iv * gv);
          c1v[j * 4 + r] = c;
          const float th = fmaf(-2.f, sig_pre(c * (2.f * L2E)), 1.f);
          hh[r] = ov * th;
        }
        const unsigned hp0 = cvtpk_bf16(hh[0], hh[1]);
        const unsigned hp1 = cvtpk_bf16(hh[2], hh[3]);
        *(ull*)(lds + LH1 + p * 4096 + wrT[j]) = ((ull)hp1 << 32) | hp0;
      }
    }
    __syncthreads();
  }

  // ---- tail: L1 step k=T -> h1(T-1) in regs (reads H1[1], H0[1]; T even) ----
  float h1f[8];
  if (!isL0) {
    bf16x8 b1f[4], b0f[4];
    #pragma unroll
    for (int kf = 0; kf < 4; ++kf) {
      b1f[kf] = *(const bf16x8*)(lds + LH1 + 4096 + kf * 1024 + rdB);
      b0f[kf] = *(const bf16x8*)(lds + LH0 + 4096 + kf * 1024 + rdB);
    }
    f32x4 acc[8];
    #pragma unroll
    for (int i = 0; i < 8; ++i)
      acc[i] = *(const f32x4*)(lds + LB1 + (v + 4 * i) * 64 + lg * 16);
    #pragma unroll
    for (int kf = 0; kf < 4; ++kf)
      #pragma unroll
      for (int i = 0; i < 8; ++i)
        acc[i] = __builtin_amdgcn_mfma_f32_16x16x32_bf16(W1r[i][kf], b1f[kf], acc[i], 0, 0, 0);
    #pragma unroll
    for (int kf = 0; kf < 4; ++kf) {
      bf16x8 af[8];
      #pragma unroll
      for (int i = 0; i < 8; ++i)
        af[i] = *(const bf16x8*)(lds + LW1 + ((v + 4 * i) * 4 + kf) * 1024 + l * 16);
      #pragma unroll
      for (int i = 0; i < 8; ++i)
        acc[i] = __builtin_amdgcn_mfma_f32_16x16x32_bf16(af[i], b0f[kf], acc[i], 0, 0, 0);
    }
    #pragma unroll
    for (int j = 0; j < 2; ++j)
      #pragma unroll
      for (int r = 0; r < 4; ++r) {
        const float iv = sig_pre(acc[0 + j][r]);
        const float fv = sig_pre(acc[2 + j][r]);
        const float gv = fmaf(-2.f, sig_pre(acc[4 + j][r]), 1.f);
        const float ov = sig_pre(acc[6 + j][r]);
        const float c  = fmaf(fv, c1v[j * 4 + r], iv * gv);
        const float th = fmaf(-2.f, sig_pre(c * (2.f * L2E)), 1.f);
        h1f[j * 4 + r] = ov * th;
      }
    // feats + dense partials
    #pragma unroll
    for (int j = 0; j < 2; ++j) {
      const int cb = v + 4 * j;
      const int colb = cb * 16 + lg * 4;
      const float4 wd4 = *(const float4*)&Wd[colb];
      const float partial = h1f[j*4+0]*wd4.x + h1f[j*4+1]*wd4.y +
                            h1f[j*4+2]*wd4.z + h1f[j*4+3]*wd4.w;
      ((float*)(lds + LRED))[lr * 32 + cb * 4 + lg] = partial;
      float4 o4;
      o4.x = h1f[j*4+0]; o4.y = h1f[j*4+1]; o4.z = h1f[j*4+2]; o4.w = h1f[j*4+3];
      *(float4*)(&out[256 + (size_t)(b0 + lr) * H + colb]) = o4;
    }
  }
  __syncthreads();
  if (tid < 16) {
    float s = 0.f;
    #pragma unroll 8
    for (int m = 0; m < 32; ++m) s += ((float*)(lds + LRED))[tid * 32 + m];
    out[b0 + tid] = __builtin_amdgcn_rcpf(1.f + EXP2(-(s + bd[0]) * L2E));
  }
}

extern "C" void kernel_launch(void* const* d_in, const int* in_sizes, int n_in,
                              void* d_out, int out_size, void* d_ws, size_t ws_size,
                              hipStream_t stream) {
  const float* x    = (const float*)d_in[0];
  // d_in[1] = seq_lengths : unused by the reference
  const float* Wih0 = (const float*)d_in[2];
  const float* Whh0 = (const float*)d_in[3];
  const float* bih0 = (const float*)d_in[4];
  const float* bhh0 = (const float*)d_in[5];
  const float* Wih1 = (const float*)d_in[6];
  const float* Whh1 = (const float*)d_in[7];
  const float* bih1 = (const float*)d_in[8];
  const float* bhh1 = (const float*)d_in[9];
  const float* Wd   = (const float*)d_in[10];
  const float* bd   = (const float*)d_in[11];
  (void)in_sizes; (void)n_in; (void)out_size; (void)d_ws; (void)ws_size;

  lstm_crew<<<dim3(16), dim3(NTHR), 0, stream>>>(
      x, Wih0, Whh0, bih0, bhh0, Wih1, Whh1, bih1, bhh1, Wd, bd, (float*)d_out);
}

// Round 10
// 3596.906 us; speedup vs baseline: 4.0048x; 2.9237x over previous
//
#include <hip/hip_runtime.h>

// R10: merged ONE-barrier fused 2-layer LSTM (R3 topology), spill-free.
// 16 blocks x 512 threads; block g owns batches [16g, 16g+16).
// Iter t computes L0(t) and L1(t-1): both consume only pre-barrier state
// {h0(t-1), h1(t-2), x(t)} -> single __syncthreads per step.
// Register diet vs R3 (which spilled at ~290 live regs):
//  - Wih1 -> 128KB LDS frag image (R9-verified layout), 16 ds_read_b128/wave/step
//  - L1 bias -> LDS f32 D-frag image (R6-verified)
//  - bfH0 frags SHARED between L0 (Whh0 h0) and L1 (Wih1 h0) MFMAs.
// Weights in regs: A0 (Whh0 + x/bias kfrag) 80 + Whh1 64 = 144 VGPR.

typedef short bf16x8 __attribute__((ext_vector_type(8)));
typedef float f32x4 __attribute__((ext_vector_type(4)));
typedef unsigned long long ull;

static constexpr int CIN = 12, T = 2048, H = 128;
static constexpr int NTHR = 512;
static constexpr float L2E = 1.4426950408889634f;

// LDS map
static constexpr int LW1 = 0;         // 131072  Wih1 frag image (pre-scaled bf16)
static constexpr int LH0 = 131072;    // 2 x 4096  h0 dbuf (B-frag image)
static constexpr int LH1 = 139264;    // 2 x 4096  h1 dbuf
static constexpr int LX  = 147456;    // 2 x 1024  x dbuf (k=12 col = 1.0 -> L0 bias)
static constexpr int LB1 = 149504;    // 2048      L1 bias f32 (pre-scaled)
static constexpr int LRED= 151552;    // 2048      epilogue reduction
static constexpr int LDS_SZ = 153600; // 150 KB (R9 proved this compiles/runs)

#if __has_builtin(__builtin_amdgcn_exp2f)
#define EXP2(x) __builtin_amdgcn_exp2f(x)
#else
#define EXP2(x) exp2f(x)
#endif

__device__ __forceinline__ unsigned f2bf(float f) {  // f32 -> bf16 bits, RTNE
  unsigned u = __builtin_bit_cast(unsigned, f);
  return (u + 0x7FFFu + ((u >> 16) & 1u)) >> 16;
}

__device__ __forceinline__ unsigned cvtpk_bf16(float lo, float hi) {
  unsigned r;
  asm("v_cvt_pk_bf16_f32 %0, %1, %2" : "=v"(r) : "v"(lo), "v"(hi));
  return r;
}

__device__ __forceinline__ float sig_pre(float a) {  // 1/(1+2^a)
  return __builtin_amdgcn_rcpf(1.f + EXP2(a));
}

__global__ __launch_bounds__(NTHR, 2) void lstm_merged(
    const float* __restrict__ xg,
    const float* __restrict__ Wih0, const float* __restrict__ Whh0,
    const float* __restrict__ bih0, const float* __restrict__ bhh0,
    const float* __restrict__ Wih1, const float* __restrict__ Whh1,
    const float* __restrict__ bih1, const float* __restrict__ bhh1,
    const float* __restrict__ Wd,   const float* __restrict__ bd,
    float* __restrict__ out)
{
  __shared__ char lds[LDS_SZ];
  const int tid = threadIdx.x;
  const int l  = tid & 63;
  const int w  = tid >> 6;   // wave 0..7
  const int lg = l >> 4;     // lane k-group 0..3
  const int lr = l & 15;     // A: row-in-tile ; B/D: batch column
  const int b0 = blockIdx.x * 16;

  // ---- zero h/x state region (LH0..LX end = 18432 B) ----
  for (int i = tid; i < 18432 / 4; i += NTHR) ((int*)(lds + LH0))[i] = 0;
  // ---- stage Wih1 -> LDS frag image (pre-scaled bf16), coalesced  [R9-verified] ----
  {
    const float4* Wv = (const float4*)Wih1;   // 16384 float4s
    #pragma unroll 4
    for (int i = 0; i < 32; ++i) {
      const int idx = i * 512 + tid;          // float4 index
      const float4 f = Wv[idx];
      const int e0 = idx * 4;                 // element index
      const int n = e0 >> 7, k = e0 & 127;    // row 0..511, col (mult of 4)
      const int tau = n >> 4;
      const float s = ((tau >> 3) == 2) ? (2.f * L2E) : (-L2E);
      const int lane = ((k >> 3) & 3) * 16 + (n & 15);
      const int byte = ((tau * 4 + (k >> 5)) * 64 + lane) * 16 + (k & 7) * 2;
      const unsigned lo = cvtpk_bf16(f.x * s, f.y * s);
      const unsigned hi = cvtpk_bf16(f.z * s, f.w * s);
      *(ull*)(lds + LW1 + byte) = ((ull)hi << 32) | lo;   // 8B, 8-aligned
    }
  }
  // ---- L1 bias image (pre-scaled f32, D-frag addressing)  [R6-verified] ----
  {
    const float s = ((tid >> 7) == 2) ? (2.f * L2E) : (-L2E);
    ((float*)(lds + LB1))[tid] = (bih1[tid] + bhh1[tid]) * s;
  }
  __syncthreads();
  // const-1.0 column at k==12 of both X buffers (pairs with L0 bias column)
  if (tid < 32) {
    const int buf = tid >> 4, b = tid & 15;
    *(unsigned short*)(lds + LX + buf * 1024 + 256 + b * 16 + 8) = 0x3F80;
  }

  // ---- weight registers: A0 (Whh0 + x/bias kfrag), A1h (Whh1) ----
  bf16x8 A0[4][5];
  bf16x8 A1h[4][4];
  #pragma unroll
  for (int q = 0; q < 4; ++q) {
    const int n = (q * 8 + w) * 16 + lr;         // global gate row
    const float s = (q == 2) ? (2.f * L2E) : (-L2E);
    #pragma unroll
    for (int kf = 0; kf < 4; ++kf) {
      const float* s0 = &Whh0[n * H + kf * 32 + lg * 8];
      const float* s1 = &Whh1[n * H + kf * 32 + lg * 8];
      #pragma unroll
      for (int j = 0; j < 8; ++j) {
        A0[q][kf][j]  = (short)f2bf(s0[j] * s);
        A1h[q][kf][j] = (short)f2bf(s1[j] * s);
      }
    }
    #pragma unroll
    for (int j = 0; j < 8; ++j) {
      const int k = lg * 8 + j;
      float v = 0.f;
      if (k < CIN) v = Wih0[n * CIN + k] * s;
      else if (k == CIN) v = (bih0[n] + bhh0[n]) * s;  // pairs with 1.0 in X
      A0[q][4][j] = (short)f2bf(v);
    }
  }
  const f32x4 zed = {0.f, 0.f, 0.f, 0.f};

  // per-lane geometry
  const int rdB  = lg * 256 + lr * 16;                       // B-frag read base
  const int bcol = w * 16 + lg * 4;                          // base h-column
  const int wrH  = (bcol >> 3) * 256 + lr * 16 + (bcol & 7) * 2;
  const int bq   = (w * 16 + lg * 4) * 4;                    // LB1 byte base (q stride 512)
  const int xb = tid & 15, xc = tid >> 4;                    // x loader (tid<192)
  const int wrX = (xc >> 3) * 256 + xb * 16 + (xc & 7) * 2;
  const size_t xbase = (size_t)(b0 + xb) * (CIN * T) + (size_t)xc * T;

  if (tid < 192)
    *(unsigned short*)(lds + LX + wrX) = (unsigned short)f2bf(xg[xbase]);
  __syncthreads();

  float c0v[4] = {0.f, 0.f, 0.f, 0.f};
  float c1v[4] = {0.f, 0.f, 0.f, 0.f};
  float h1v[4] = {0.f, 0.f, 0.f, 0.f};

  // Iter t: L0(t) (h0(t-1), x(t)) and L1(t-1) (h1(t-2), h0(t-1)).
  // read H0[1-p], H1[p], X[p]; write H0[p], H1[1-p], X[1-p]. One barrier.
  #pragma unroll 2
  for (int t = 0; t < T; ++t) {
    const int p = t & 1;
    float xnext = 0.f;
    if (tid < 192) xnext = xg[xbase + (t + 1 < T ? t + 1 : t)];

    bf16x8 bfH0[4], bfH1[4], bfX;
    #pragma unroll
    for (int kf = 0; kf < 4; ++kf) {
      bfH0[kf] = *(const bf16x8*)(lds + LH0 + (1 - p) * 4096 + kf * 1024 + rdB);
      bfH1[kf] = *(const bf16x8*)(lds + LH1 + p * 4096 + kf * 1024 + rdB);
    }
    bfX = *(const bf16x8*)(lds + LX + p * 1024 + rdB);

    f32x4 accA[4], accB[4];
    #pragma unroll
    for (int q = 0; q < 4; ++q) {
      accA[q] = zed;
      accB[q] = *(const f32x4*)(lds + LB1 + bq + q * 512);   // L1 bias (D-frag rows)
    }
    #pragma unroll
    for (int kf = 0; kf < 4; ++kf) {
      bf16x8 af[4];                                          // Wih1 frags from LDS
      #pragma unroll
      for (int q = 0; q < 4; ++q)
        af[q] = *(const bf16x8*)(lds + LW1 + ((q * 8 + w) * 4 + kf) * 1024 + l * 16);
      #pragma unroll
      for (int q = 0; q < 4; ++q) {
        accA[q] = __builtin_amdgcn_mfma_f32_16x16x32_bf16(A0[q][kf],  bfH0[kf], accA[q], 0, 0, 0);
        accB[q] = __builtin_amdgcn_mfma_f32_16x16x32_bf16(A1h[q][kf], bfH1[kf], accB[q], 0, 0, 0);
        accB[q] = __builtin_amdgcn_mfma_f32_16x16x32_bf16(af[q],      bfH0[kf], accB[q], 0, 0, 0);
      }
    }
    #pragma unroll
    for (int q = 0; q < 4; ++q)
      accA[q] = __builtin_amdgcn_mfma_f32_16x16x32_bf16(A0[q][4], bfX, accA[q], 0, 0, 0);

    // ---- elementwise L0 -> h0(t) ----
    {
      float h0t[4];
      #pragma unroll
      for (int r = 0; r < 4; ++r) {
        const float iv = sig_pre(accA[0][r]);
        const float fv = sig_pre(accA[1][r]);
        const float gv = fmaf(-2.f, sig_pre(accA[2][r]), 1.f);
        const float ov = sig_pre(accA[3][r]);
        const float c  = fmaf(fv, c0v[r], iv * gv);
        c0v[r] = c;
        const float th = fmaf(-2.f, sig_pre(c * (2.f * L2E)), 1.f);
        h0t[r] = ov * th;
      }
      const unsigned hp0 = cvtpk_bf16(h0t[0], h0t[1]);
      const unsigned hp1 = cvtpk_bf16(h0t[2], h0t[3]);
      *(ull*)(lds + LH0 + p * 4096 + wrH) = ((ull)hp1 << 32) | hp0;
    }
    // ---- elementwise L1 -> h1(t-1) (skip at t==0: keep h1(-1)=0) ----
    if (t > 0) {
      #pragma unroll
      for (int r = 0; r < 4; ++r) {
        const float iv = sig_pre(accB[0][r]);
        const float fv = sig_pre(accB[1][r]);
        const float gv = fmaf(-2.f, sig_pre(accB[2][r]), 1.f);
        const float ov = sig_pre(accB[3][r]);
        const float c  = fmaf(fv, c1v[r], iv * gv);
        c1v[r] = c;
        const float th = fmaf(-2.f, sig_pre(c * (2.f * L2E)), 1.f);
        h1v[r] = ov * th;
      }
      const unsigned hp0 = cvtpk_bf16(h1v[0], h1v[1]);
      const unsigned hp1 = cvtpk_bf16(h1v[2], h1v[3]);
      *(ull*)(lds + LH1 + (1 - p) * 4096 + wrH) = ((ull)hp1 << 32) | hp0;
    }
    if (tid < 192) {
      *(unsigned short*)(lds + LX + (1 - p) * 1024 + wrX) =
          (unsigned short)cvtpk_bf16(xnext, xnext);
    }
    __syncthreads();
  }

  // ---- peeled final L1 step: h1(T-1) <- h1(T-2), h0(T-1) ----
  // T even: h0(T-1) in H0[1], h1(T-2) in H1[0].
  {
    bf16x8 bfH0[4], bfH1[4];
    #pragma unroll
    for (int kf = 0; kf < 4; ++kf) {
      bfH0[kf] = *(const bf16x8*)(lds + LH0 + 4096 + kf * 1024 + rdB);
      bfH1[kf] = *(const bf16x8*)(lds + LH1 + kf * 1024 + rdB);
    }
    f32x4 accB[4];
    #pragma unroll
    for (int q = 0; q < 4; ++q)
      accB[q] = *(const f32x4*)(lds + LB1 + bq + q * 512);
    #pragma unroll
    for (int kf = 0; kf < 4; ++kf) {
      bf16x8 af[4];
      #pragma unroll
      for (int q = 0; q < 4; ++q)
        af[q] = *(const bf16x8*)(lds + LW1 + ((q * 8 + w) * 4 + kf) * 1024 + l * 16);
      #pragma unroll
      for (int q = 0; q < 4; ++q) {
        accB[q] = __builtin_amdgcn_mfma_f32_16x16x32_bf16(A1h[q][kf], bfH1[kf], accB[q], 0, 0, 0);
        accB[q] = __builtin_amdgcn_mfma_f32_16x16x32_bf16(af[q],      bfH0[kf], accB[q], 0, 0, 0);
      }
    }
    #pragma unroll
    for (int r = 0; r < 4; ++r) {
      const float iv = sig_pre(accB[0][r]);
      const float fv = sig_pre(accB[1][r]);
      const float gv = fmaf(-2.f, sig_pre(accB[2][r]), 1.f);
      const float ov = sig_pre(accB[3][r]);
      const float c  = fmaf(fv, c1v[r], iv * gv);
      c1v[r] = c;
      const float th = fmaf(-2.f, sig_pre(c * (2.f * L2E)), 1.f);
      h1v[r] = ov * th;
    }
  }

  // ---- epilogue: feats = h1(T-1), scores = sigmoid(h1 . Wd + bd) ----
  const float4 wd = *(const float4*)&Wd[bcol];
  const float partial = h1v[0] * wd.x + h1v[1] * wd.y + h1v[2] * wd.z + h1v[3] * wd.w;
  #pragma unroll
  for (int r = 0; r < 4; ++r)
    out[256 + (size_t)(b0 + lr) * H + (bcol + r)] = h1v[r];
  ((float*)(lds + LRED))[tid] = partial;
  __syncthreads();
  if (tid < 16) {
    float s = 0.f;
    #pragma unroll 8
    for (int k = 0; k < 32; ++k) s += ((float*)(lds + LRED))[tid + 16 * k];
    const float v = s + bd[0];
    out[b0 + tid] = __builtin_amdgcn_rcpf(1.f + EXP2(-v * L2E));
  }
}

extern "C" void kernel_launch(void* const* d_in, const int* in_sizes, int n_in,
                              void* d_out, int out_size, void* d_ws, size_t ws_size,
                              hipStream_t stream) {
  const float* x    = (const float*)d_in[0];
  // d_in[1] = seq_lengths : unused by the reference
  const float* Wih0 = (const float*)d_in[2];
  const float* Whh0 = (const float*)d_in[3];
  const float* bih0 = (const float*)d_in[4];
  const float* bhh0 = (const float*)d_in[5];
  const float* Wih1 = (const float*)d_in[6];
  const float* Whh1 = (const float*)d_in[7];
  const float* bih1 = (const float*)d_in[8];
  const float* bhh1 = (const float*)d_in[9];
  const float* Wd   = (const float*)d_in[10];
  const float* bd   = (const float*)d_in[11];
  (void)in_sizes; (void)n_in; (void)out_size; (void)d_ws; (void)ws_size;

  lstm_merged<<<dim3(16), dim3(NTHR), 0, stream>>>(
      x, Wih0, Whh0, bih0, bhh0, Wih1, Whh1, bih1, bhh1, Wd, bd, (float*)d_out);
}

// Round 11
// 3406.688 us; speedup vs baseline: 4.2284x; 1.0558x over previous
//
#include <hip/hip_runtime.h>

// R11: R10 merged one-barrier topology + MFMA/VALU overlap reordering.
// Per step, program order: accA MFMAs -> ew-L0 (+h0 publish) -> accB MFMAs
// -> ew-L1. ew-L0's trans chain and accB's 32 independent MFMAs co-schedule
// (m114: MFMA and VALU pipes are concurrent when fed independently).
// L1 bias hoisted LDS -> regs (b1r, 16 VGPR) to cut per-step LDS traffic.
// Everything else identical to R10 (passed, absmax 3.9e-3, spill-free).

typedef short bf16x8 __attribute__((ext_vector_type(8)));
typedef float f32x4 __attribute__((ext_vector_type(4)));
typedef unsigned long long ull;

static constexpr int CIN = 12, T = 2048, H = 128;
static constexpr int NTHR = 512;
static constexpr float L2E = 1.4426950408889634f;

// LDS map
static constexpr int LW1 = 0;         // 131072  Wih1 frag image (pre-scaled bf16)
static constexpr int LH0 = 131072;    // 2 x 4096  h0 dbuf (B-frag image)
static constexpr int LH1 = 139264;    // 2 x 4096  h1 dbuf
static constexpr int LX  = 147456;    // 2 x 1024  x dbuf (k=12 col = 1.0 -> L0 bias)
static constexpr int LRED= 149504;    // 2048      epilogue reduction
static constexpr int LDS_SZ = 151552; // 148 KB

#if __has_builtin(__builtin_amdgcn_exp2f)
#define EXP2(x) __builtin_amdgcn_exp2f(x)
#else
#define EXP2(x) exp2f(x)
#endif

__device__ __forceinline__ unsigned f2bf(float f) {  // f32 -> bf16 bits, RTNE
  unsigned u = __builtin_bit_cast(unsigned, f);
  return (u + 0x7FFFu + ((u >> 16) & 1u)) >> 16;
}

__device__ __forceinline__ unsigned cvtpk_bf16(float lo, float hi) {
  unsigned r;
  asm("v_cvt_pk_bf16_f32 %0, %1, %2" : "=v"(r) : "v"(lo), "v"(hi));
  return r;
}

__device__ __forceinline__ float sig_pre(float a) {  // 1/(1+2^a)
  return __builtin_amdgcn_rcpf(1.f + EXP2(a));
}

__global__ __launch_bounds__(NTHR, 2) void lstm_merged(
    const float* __restrict__ xg,
    const float* __restrict__ Wih0, const float* __restrict__ Whh0,
    const float* __restrict__ bih0, const float* __restrict__ bhh0,
    const float* __restrict__ Wih1, const float* __restrict__ Whh1,
    const float* __restrict__ bih1, const float* __restrict__ bhh1,
    const float* __restrict__ Wd,   const float* __restrict__ bd,
    float* __restrict__ out)
{
  __shared__ char lds[LDS_SZ];
  const int tid = threadIdx.x;
  const int l  = tid & 63;
  const int w  = tid >> 6;   // wave 0..7
  const int lg = l >> 4;     // lane k-group 0..3
  const int lr = l & 15;     // A: row-in-tile ; B/D: batch column
  const int b0 = blockIdx.x * 16;

  // ---- zero h/x state region (LH0..LX end = 18432 B) ----
  for (int i = tid; i < 18432 / 4; i += NTHR) ((int*)(lds + LH0))[i] = 0;
  // ---- stage Wih1 -> LDS frag image (pre-scaled bf16), coalesced [R9-verified] ----
  {
    const float4* Wv = (const float4*)Wih1;   // 16384 float4s
    #pragma unroll 4
    for (int i = 0; i < 32; ++i) {
      const int idx = i * 512 + tid;          // float4 index
      const float4 f = Wv[idx];
      const int e0 = idx * 4;                 // element index
      const int n = e0 >> 7, k = e0 & 127;    // row 0..511, col (mult of 4)
      const int tau = n >> 4;
      const float s = ((tau >> 3) == 2) ? (2.f * L2E) : (-L2E);
      const int lane = ((k >> 3) & 3) * 16 + (n & 15);
      const int byte = ((tau * 4 + (k >> 5)) * 64 + lane) * 16 + (k & 7) * 2;
      const unsigned lo = cvtpk_bf16(f.x * s, f.y * s);
      const unsigned hi = cvtpk_bf16(f.z * s, f.w * s);
      *(ull*)(lds + LW1 + byte) = ((ull)hi << 32) | lo;   // 8B, 8-aligned
    }
  }
  __syncthreads();
  // const-1.0 column at k==12 of both X buffers (pairs with L0 bias column)
  if (tid < 32) {
    const int buf = tid >> 4, b = tid & 15;
    *(unsigned short*)(lds + LX + buf * 1024 + 256 + b * 16 + 8) = 0x3F80;
  }

  // ---- weight registers: A0 (Whh0 + x/bias kfrag), A1h (Whh1), b1r (L1 bias) ----
  bf16x8 A0[4][5];
  bf16x8 A1h[4][4];
  f32x4 b1r[4];
  #pragma unroll
  for (int q = 0; q < 4; ++q) {
    const int n = (q * 8 + w) * 16 + lr;         // global gate row
    const float s = (q == 2) ? (2.f * L2E) : (-L2E);
    #pragma unroll
    for (int kf = 0; kf < 4; ++kf) {
      const float* s0 = &Whh0[n * H + kf * 32 + lg * 8];
      const float* s1 = &Whh1[n * H + kf * 32 + lg * 8];
      #pragma unroll
      for (int j = 0; j < 8; ++j) {
        A0[q][kf][j]  = (short)f2bf(s0[j] * s);
        A1h[q][kf][j] = (short)f2bf(s1[j] * s);
      }
    }
    #pragma unroll
    for (int j = 0; j < 8; ++j) {
      const int k = lg * 8 + j;
      float v = 0.f;
      if (k < CIN) v = Wih0[n * CIN + k] * s;
      else if (k == CIN) v = (bih0[n] + bhh0[n]) * s;  // pairs with 1.0 in X
      A0[q][4][j] = (short)f2bf(v);
    }
    #pragma unroll
    for (int r = 0; r < 4; ++r) {
      const int nd = (q * 8 + w) * 16 + lg * 4 + r;   // D-frag row for this lane
      b1r[q][r] = (bih1[nd] + bhh1[nd]) * s;
    }
  }
  const f32x4 zed = {0.f, 0.f, 0.f, 0.f};

  // per-lane geometry
  const int rdB  = lg * 256 + lr * 16;                       // B-frag read base
  const int bcol = w * 16 + lg * 4;                          // base h-column
  const int wrH  = (bcol >> 3) * 256 + lr * 16 + (bcol & 7) * 2;
  const int xb = tid & 15, xc = tid >> 4;                    // x loader (tid<192)
  const int wrX = (xc >> 3) * 256 + xb * 16 + (xc & 7) * 2;
  const size_t xbase = (size_t)(b0 + xb) * (CIN * T) + (size_t)xc * T;

  if (tid < 192)
    *(unsigned short*)(lds + LX + wrX) = (unsigned short)f2bf(xg[xbase]);
  __syncthreads();

  float c0v[4] = {0.f, 0.f, 0.f, 0.f};
  float c1v[4] = {0.f, 0.f, 0.f, 0.f};
  float h1v[4] = {0.f, 0.f, 0.f, 0.f};

  // Iter t: L0(t) (h0(t-1), x(t)) and L1(t-1) (h1(t-2), h0(t-1)).
  // read H0[1-p], H1[p], X[p]; write H0[p], H1[1-p], X[1-p]. One barrier.
  // Order: accA -> ew-L0 (+publish h0) -> accB -> ew-L1 : ew-L0's VALU/trans
  // chain co-schedules with accB's independent MFMAs.
  #pragma unroll 2
  for (int t = 0; t < T; ++t) {
    const int p = t & 1;
    float xnext = 0.f;
    if (tid < 192) xnext = xg[xbase + (t + 1 < T ? t + 1 : t)];

    bf16x8 bfH0[4], bfH1[4], bfX;
    #pragma unroll
    for (int kf = 0; kf < 4; ++kf) {
      bfH0[kf] = *(const bf16x8*)(lds + LH0 + (1 - p) * 4096 + kf * 1024 + rdB);
      bfH1[kf] = *(const bf16x8*)(lds + LH1 + p * 4096 + kf * 1024 + rdB);
    }
    bfX = *(const bf16x8*)(lds + LX + p * 1024 + rdB);

    // ---- phase 1: accA (L0 pre-activations) ----
    f32x4 accA[4];
    #pragma unroll
    for (int q = 0; q < 4; ++q) accA[q] = zed;
    #pragma unroll
    for (int kf = 0; kf < 4; ++kf)
      #pragma unroll
      for (int q = 0; q < 4; ++q)
        accA[q] = __builtin_amdgcn_mfma_f32_16x16x32_bf16(A0[q][kf], bfH0[kf], accA[q], 0, 0, 0);
    #pragma unroll
    for (int q = 0; q < 4; ++q)
      accA[q] = __builtin_amdgcn_mfma_f32_16x16x32_bf16(A0[q][4], bfX, accA[q], 0, 0, 0);

    // ---- phase 2: ew-L0 + publish h0(t) (overlaps phase-3 MFMAs) ----
    {
      float h0t[4];
      #pragma unroll
      for (int r = 0; r < 4; ++r) {
        const float iv = sig_pre(accA[0][r]);
        const float fv = sig_pre(accA[1][r]);
        const float gv = fmaf(-2.f, sig_pre(accA[2][r]), 1.f);
        const float ov = sig_pre(accA[3][r]);
        const float c  = fmaf(fv, c0v[r], iv * gv);
        c0v[r] = c;
        const float th = fmaf(-2.f, sig_pre(c * (2.f * L2E)), 1.f);
        h0t[r] = ov * th;
      }
      const unsigned hp0 = cvtpk_bf16(h0t[0], h0t[1]);
      const unsigned hp1 = cvtpk_bf16(h0t[2], h0t[3]);
      *(ull*)(lds + LH0 + p * 4096 + wrH) = ((ull)hp1 << 32) | hp0;
    }

    // ---- phase 3: accB (L1 pre-activations; independent of ew-L0) ----
    f32x4 accB[4];
    #pragma unroll
    for (int q = 0; q < 4; ++q) accB[q] = b1r[q];
    #pragma unroll
    for (int kf = 0; kf < 4; ++kf) {
      bf16x8 af[4];                                          // Wih1 frags from LDS
      #pragma unroll
      for (int q = 0; q < 4; ++q)
        af[q] = *(const bf16x8*)(lds + LW1 + ((q * 8 + w) * 4 + kf) * 1024 + l * 16);
      #pragma unroll
      for (int q = 0; q < 4; ++q) {
        accB[q] = __builtin_amdgcn_mfma_f32_16x16x32_bf16(A1h[q][kf], bfH1[kf], accB[q], 0, 0, 0);
        accB[q] = __builtin_amdgcn_mfma_f32_16x16x32_bf16(af[q],      bfH0[kf], accB[q], 0, 0, 0);
      }
    }

    // ---- phase 4: ew-L1 -> h1(t-1) (skip at t==0: keep h1(-1)=0) ----
    if (t > 0) {
      #pragma unroll
      for (int r = 0; r < 4; ++r) {
        const float iv = sig_pre(accB[0][r]);
        const float fv = sig_pre(accB[1][r]);
        const float gv = fmaf(-2.f, sig_pre(accB[2][r]), 1.f);
        const float ov = sig_pre(accB[3][r]);
        const float c  = fmaf(fv, c1v[r], iv * gv);
        c1v[r] = c;
        const float th = fmaf(-2.f, sig_pre(c * (2.f * L2E)), 1.f);
        h1v[r] = ov * th;
      }
      const unsigned hp0 = cvtpk_bf16(h1v[0], h1v[1]);
      const unsigned hp1 = cvtpk_bf16(h1v[2], h1v[3]);
      *(ull*)(lds + LH1 + (1 - p) * 4096 + wrH) = ((ull)hp1 << 32) | hp0;
    }
    if (tid < 192) {
      *(unsigned short*)(lds + LX + (1 - p) * 1024 + wrX) =
          (unsigned short)cvtpk_bf16(xnext, xnext);
    }
    __syncthreads();
  }

  // ---- peeled final L1 step: h1(T-1) <- h1(T-2), h0(T-1) ----
  // T even: h0(T-1) in H0[1], h1(T-2) in H1[0].
  {
    bf16x8 bfH0[4], bfH1[4];
    #pragma unroll
    for (int kf = 0; kf < 4; ++kf) {
      bfH0[kf] = *(const bf16x8*)(lds + LH0 + 4096 + kf * 1024 + rdB);
      bfH1[kf] = *(const bf16x8*)(lds + LH1 + kf * 1024 + rdB);
    }
    f32x4 accB[4];
    #pragma unroll
    for (int q = 0; q < 4; ++q) accB[q] = b1r[q];
    #pragma unroll
    for (int kf = 0; kf < 4; ++kf) {
      bf16x8 af[4];
      #pragma unroll
      for (int q = 0; q < 4; ++q)
        af[q] = *(const bf16x8*)(lds + LW1 + ((q * 8 + w) * 4 + kf) * 1024 + l * 16);
      #pragma unroll
      for (int q = 0; q < 4; ++q) {
        accB[q] = __builtin_amdgcn_mfma_f32_16x16x32_bf16(A1h[q][kf], bfH1[kf], accB[q], 0, 0, 0);
        accB[q] = __builtin_amdgcn_mfma_f32_16x16x32_bf16(af[q],      bfH0[kf], accB[q], 0, 0, 0);
      }
    }
    #pragma unroll
    for (int r = 0; r < 4; ++r) {
      const float iv = sig_pre(accB[0][r]);
      const float fv = sig_pre(accB[1][r]);
      const float gv = fmaf(-2.f, sig_pre(accB[2][r]), 1.f);
      const float ov = sig_pre(accB[3][r]);
      const float c  = fmaf(fv, c1v[r], iv * gv);
      c1v[r] = c;
      const float th = fmaf(-2.f, sig_pre(c * (2.f * L2E)), 1.f);
      h1v[r] = ov * th;
    }
  }

  // ---- epilogue: feats = h1(T-1), scores = sigmoid(h1 . Wd + bd) ----
  const float4 wd = *(const float4*)&Wd[bcol];
  const float partial = h1v[0] * wd.x + h1v[1] * wd.y + h1v[2] * wd.z + h1v[3] * wd.w;
  #pragma unroll
  for (int r = 0; r < 4; ++r)
    out[256 + (size_t)(b0 + lr) * H + (bcol + r)] = h1v[r];
  ((float*)(lds + LRED))[tid] = partial;
  __syncthreads();
  if (tid < 16) {
    float s = 0.f;
    #pragma unroll 8
    for (int k = 0; k < 32; ++k) s += ((float*)(lds + LRED))[tid + 16 * k];
    const float v = s + bd[0];
    out[b0 + tid] = __builtin_amdgcn_rcpf(1.f + EXP2(-v * L2E));
  }
}

extern "C" void kernel_launch(void* const* d_in, const int* in_sizes, int n_in,
                              void* d_out, int out_size, void* d_ws, size_t ws_size,
                              hipStream_t stream) {
  const float* x    = (const float*)d_in[0];
  // d_in[1] = seq_lengths : unused by the reference
  const float* Wih0 = (const float*)d_in[2];
  const float* Whh0 = (const float*)d_in[3];
  const float* bih0 = (const float*)d_in[4];
  const float* bhh0 = (const float*)d_in[5];
  const float* Wih1 = (const float*)d_in[6];
  const float* Whh1 = (const float*)d_in[7];
  const float* bih1 = (const float*)d_in[8];
  const float* bhh1 = (const float*)d_in[9];
  const float* Wd   = (const float*)d_in[10];
  const float* bd   = (const float*)d_in[11];
  (void)in_sizes; (void)n_in; (void)out_size; (void)d_ws; (void)ws_size;

  lstm_merged<<<dim3(16), dim3(NTHR), 0, stream>>>(
      x, Wih0, Whh0, bih0, bhh0, Wih1, Whh1, bih1, bhh1, Wd, bd, (float*)d_out);
}